// Round 3
// baseline (887.135 us; speedup 1.0000x reference)
//
#include <hip/hip_runtime.h>
#include <hip/hip_bf16.h>
#include <math.h>

// Problem constants (N=4, S=2048, D=1024, H=16, DK=64)
#define SEQ    2048
#define DMODEL 1024
#define NHEAD  16
#define HDIM   64
#define NH_TOT 64            // N * NHEAD
#define SCALE  0.125f        // 1/sqrt(64)

typedef __attribute__((ext_vector_type(8))) short bf16x8;  // 8 bf16 = 4 VGPRs
typedef __attribute__((ext_vector_type(4))) float f32x4;

#define MFMA16(a, b, c) __builtin_amdgcn_mfma_f32_16x16x32_bf16((a), (b), (c), 0, 0, 0)

// float -> bf16 bits, round-to-nearest-even
__device__ __forceinline__ unsigned f2bf_bits(float f) {
    unsigned u = __float_as_uint(f);
    return (u + 0x7fffu + ((u >> 16) & 1u)) >> 16;
}
__device__ __forceinline__ float bf2f(unsigned bits) {
    return __uint_as_float(bits << 16);
}
// hi/lo split: f ~= bf16(hi) + bf16(lo), residual ~2^-17 relative
__device__ __forceinline__ void split2(float f, unsigned& hb, unsigned& lb) {
    hb = f2bf_bits(f);
    lb = f2bf_bits(f - bf2f(hb));
}
__device__ __forceinline__ void split_store8(const float4& a0, const float4& a1,
                                             short* ph, short* pl) {
    const float f[8] = {a0.x, a0.y, a0.z, a0.w, a1.x, a1.y, a1.z, a1.w};
    bf16x8 hv, lv;
    #pragma unroll
    for (int j = 0; j < 8; ++j) {
        unsigned hb, lb;
        split2(f[j], hb, lb);
        hv[j] = (short)hb;
        lv[j] = (short)lb;
    }
    *(bf16x8*)ph = hv;
    *(bf16x8*)pl = lv;
}

#define GSB 40   // LDS row stride (shorts) for 32-wide tiles: 80 B rows
#define TSB 72   // LDS row stride (shorts) for 64-wide tiles: 144 B rows

// ===========================================================================
// ============================ FAST PATH (144 MiB) ==========================
// ===========================================================================

// ---------------------------------------------------------------------------
// presplit_w_k: W fp32 [1024][1024] -> split bf16 [1024][2048] (cols: hi|lo)
// blockIdx.y selects which of the 4 weight matrices.
// ---------------------------------------------------------------------------
__global__ __launch_bounds__(256) void presplit_w_k(
    const float* __restrict__ Wq, const float* __restrict__ Wk,
    const float* __restrict__ Wv, const float* __restrict__ Wp,
    short* __restrict__ Oq, short* __restrict__ Ok,
    short* __restrict__ Ov, short* __restrict__ Op)
{
    const int t = blockIdx.y;
    const float* src = (t == 0) ? Wq : (t == 1) ? Wk : (t == 2) ? Wv : Wp;
    short*       dst = (t == 0) ? Oq : (t == 1) ? Ok : (t == 2) ? Ov : Op;
    const int idx = (blockIdx.x * 256 + threadIdx.x) * 8;   // < 1M
    const int row = idx >> 10, c = idx & 1023;
    const float4 f0 = *(const float4*)(src + idx);
    const float4 f1 = *(const float4*)(src + idx + 4);
    split_store8(f0, f1, &dst[(size_t)row * 2048 + c],
                         &dst[(size_t)row * 2048 + 1024 + c]);
}

// ---------------------------------------------------------------------------
// qkv2_k: 3-term split GEMM.  C[m,e] = sum_k x[m,k]*W[e,k] + b[e]
// Block 128m x 128e, BK=32, 4 waves (2m x 2e), per-wave 64x64 (4x4 frags).
// A (x) split in-staging; B pre-split copy. Per k-step/wave: 48 MFMA, 16 ds_read.
// Epilogue: mat0 -> Qh/Ql (pre-scaled by SCALE); mat1 -> Kh/Kl;
//           mat2 -> Vth/Vtl transposed [nh][dk][s] via in-LDS 128x128 transpose.
// ---------------------------------------------------------------------------
__global__ __launch_bounds__(256) void qkv2_k(
    const float* __restrict__ x,
    const short* __restrict__ Wqs, const short* __restrict__ Wks,
    const short* __restrict__ Wvs,
    const float* __restrict__ bq, const float* __restrict__ bk,
    const float* __restrict__ bv,
    short* __restrict__ Qh, short* __restrict__ Ql,
    short* __restrict__ Kh, short* __restrict__ Kl,
    short* __restrict__ Vth, short* __restrict__ Vtl)
{
    __shared__ short smem[4 * 128 * GSB];          // 40960 B
    short (*Ash)[GSB] = (short(*)[GSB])smem;
    short (*Asl)[GSB] = (short(*)[GSB])(smem + 128 * GSB);
    short (*Bsh)[GSB] = (short(*)[GSB])(smem + 2 * 128 * GSB);
    short (*Bsl)[GSB] = (short(*)[GSB])(smem + 3 * 128 * GSB);

    const int tid  = threadIdx.x;
    const int lane = tid & 63;
    const int wv   = tid >> 6;
    const int col  = lane & 15;
    const int g    = lane >> 4;
    const int wm   = wv & 1, we = wv >> 1;

    const int m0  = blockIdx.x * 128;
    const int by  = blockIdx.y;                    // 0..23
    const int mat = by >> 3;                       // 0=Q 1=K 2=V (block-uniform)
    const int e0  = (by & 7) * 128;                // col base within matrix

    const short* Ws   = (mat == 0) ? Wqs : (mat == 1) ? Wks : Wvs;
    const float* bias = (mat == 0) ? bq  : (mat == 1) ? bk  : bv;

    // staging map: [128][32] tile, 4 threads/row, 64 rows/round, 2 rounds
    const int sr = tid >> 2, sc = (tid & 3) * 8;
    const float* Ax = x  + (size_t)m0 * DMODEL;
    const short* Bw = Ws + (size_t)e0 * 2048;

    const f32x4 fzero = {0.f, 0.f, 0.f, 0.f};
    f32x4 acc[4][4];
    #pragma unroll
    for (int i = 0; i < 4; ++i)
        #pragma unroll
        for (int j = 0; j < 4; ++j) acc[i][j] = fzero;

    for (int kt = 0; kt < DMODEL; kt += 32) {
        float4 a0[2], a1[2];
        bf16x8 pbh[2], pbl[2];
        #pragma unroll
        for (int f = 0; f < 2; ++f) {
            const float* ap = Ax + (size_t)(sr + 64 * f) * DMODEL + kt + sc;
            a0[f] = *(const float4*)ap;
            a1[f] = *(const float4*)(ap + 4);
            const short* bp = Bw + (size_t)(sr + 64 * f) * 2048 + kt + sc;
            pbh[f] = *(const bf16x8*)bp;
            pbl[f] = *(const bf16x8*)(bp + 1024);
        }
        __syncthreads();                           // prev iter frag reads done
        #pragma unroll
        for (int f = 0; f < 2; ++f) {
            split_store8(a0[f], a1[f], &Ash[sr + 64 * f][sc], &Asl[sr + 64 * f][sc]);
            *(bf16x8*)&Bsh[sr + 64 * f][sc] = pbh[f];
            *(bf16x8*)&Bsl[sr + 64 * f][sc] = pbl[f];
        }
        __syncthreads();

        bf16x8 fah[4], fal[4], fbh[4], fbl[4];
        #pragma unroll
        for (int i = 0; i < 4; ++i) {
            fah[i] = *(const bf16x8*)&Ash[64 * wm + 16 * i + col][8 * g];
            fal[i] = *(const bf16x8*)&Asl[64 * wm + 16 * i + col][8 * g];
        }
        #pragma unroll
        for (int j = 0; j < 4; ++j) {
            fbh[j] = *(const bf16x8*)&Bsh[64 * we + 16 * j + col][8 * g];
            fbl[j] = *(const bf16x8*)&Bsl[64 * we + 16 * j + col][8 * g];
        }
        #pragma unroll
        for (int i = 0; i < 4; ++i)
            #pragma unroll
            for (int j = 0; j < 4; ++j) {
                acc[i][j] = MFMA16(fah[i], fbh[j], acc[i][j]);
                acc[i][j] = MFMA16(fal[i], fbh[j], acc[i][j]);
                acc[i][j] = MFMA16(fah[i], fbl[j], acc[i][j]);
            }
    }

    const int n  = m0 >> 11;                       // batch
    const int s0 = m0 & (SEQ - 1);

    if (mat <= 1) {
        short* Dh = (mat == 0) ? Qh : Kh;
        short* Dl = (mat == 0) ? Ql : Kl;
        const float sc2 = (mat == 0) ? SCALE : 1.0f;
        #pragma unroll
        for (int i = 0; i < 4; ++i)
            #pragma unroll
            for (int j = 0; j < 4; ++j) {
                const int em = e0 + 64 * we + 16 * j + col;   // 0..1023
                const int h = em >> 6, dk = em & 63;
                const int nh = n * NHEAD + h;
                const float bb = bias[em];
                #pragma unroll
                for (int r = 0; r < 4; ++r) {
                    const int s = s0 + 64 * wm + 16 * i + 4 * g + r;
                    const float val = (acc[i][j][r] + bb) * sc2;
                    unsigned hb, lb;
                    split2(val, hb, lb);
                    const size_t o = ((size_t)nh * SEQ + s) * HDIM + dk;
                    Dh[o] = (short)hb;
                    Dl[o] = (short)lb;
                }
            }
    } else {
        // V: transpose 128x128 through LDS (reuse staging buffer), 2 planes
        short (*T)[136] = (short(*)[136])smem;     // 128*136 = 17408 shorts <= 20480
        __syncthreads();                           // all frag reads done
        #pragma unroll
        for (int plane = 0; plane < 2; ++plane) {
            if (plane) __syncthreads();            // plane-0 reads done
            #pragma unroll
            for (int i = 0; i < 4; ++i)
                #pragma unroll
                for (int j = 0; j < 4; ++j) {
                    const int em  = e0 + 64 * we + 16 * j + col;
                    const int dkl = 64 * we + 16 * j + col;   // local col 0..127
                    const float bb = bias[em];
                    #pragma unroll
                    for (int r = 0; r < 4; ++r) {
                        const int sl = 64 * wm + 16 * i + 4 * g + r;
                        unsigned hb, lb;
                        split2(acc[i][j][r] + bb, hb, lb);
                        T[dkl][sl] = (short)(plane ? lb : hb);
                    }
                }
            __syncthreads();
            const int tr  = tid >> 1;              // 0..127 (local dk row)
            const int tc0 = (tid & 1) * 64;
            const int em  = e0 + tr;
            const int h = em >> 6, dk = em & 63;
            const int nh = n * NHEAD + h;
            short* dst = (plane ? Vtl : Vth) + ((size_t)nh * HDIM + dk) * SEQ + s0 + tc0;
            #pragma unroll
            for (int f = 0; f < 8; ++f)
                *(bf16x8*)&dst[8 * f] = *(const bf16x8*)&T[tr][tc0 + 8 * f];
        }
    }
}

// ---------------------------------------------------------------------------
// attn2_k: flash attention; Q/K/V all pre-split (Q pre-scaled).
// Block: 64 q-rows x one nh. 4 waves, wave w owns q-rows [16w,16w+16).
// t-tiles of 32. y written fp32 to separate buffer.
// ---------------------------------------------------------------------------
__global__ __launch_bounds__(256) void attn2_k(
    const short* __restrict__ Qhg, const short* __restrict__ Qlg,
    const short* __restrict__ Khg, const short* __restrict__ Klg,
    const short* __restrict__ Vthg, const short* __restrict__ Vtlg,
    float* __restrict__ Yb)
{
    __shared__ short Qhs[64][TSB], Qls[64][TSB];   // [q][dk] (pre-scaled)
    __shared__ short Khs[32][TSB], Kls[32][TSB];   // [t][dk]
    __shared__ short Vhs[64][GSB], Vls[64][GSB];   // [dk][t]
    __shared__ float Ps[64][36];                   // [q][t] fp32 P tile

    const int tid  = threadIdx.x;
    const int lane = tid & 63;
    const int wv   = tid >> 6;
    const int col  = lane & 15;
    const int g    = lane >> 4;
    const int q0   = blockIdx.x * 64;
    const int nh   = blockIdx.y;

    const size_t qb  = (size_t)nh * SEQ * HDIM;
    const size_t vtb = (size_t)nh * HDIM * SEQ;

    // stage Q (pure copy of pre-split, pre-scaled bf16)
    {
        const int rq = tid >> 3, kc = (tid & 7) * 8;
        #pragma unroll
        for (int half = 0; half < 2; ++half) {
            const int rr = half * 32 + rq;
            const size_t src = qb + (size_t)(q0 + rr) * HDIM + kc;
            *(bf16x8*)&Qhs[rr][kc] = *(const bf16x8*)&Qhg[src];
            *(bf16x8*)&Qls[rr][kc] = *(const bf16x8*)&Qlg[src];
        }
    }

    const f32x4 fzero = {0.f, 0.f, 0.f, 0.f};
    f32x4 O[4];
    float m_[4], l_[4];
    #pragma unroll
    for (int d = 0; d < 4; ++d) O[d] = fzero;
    #pragma unroll
    for (int r = 0; r < 4; ++r) { m_[r] = -1e30f; l_[r] = 0.f; }

    const int kr = tid >> 3, kc8 = (tid & 7) * 8;  // K: [32][64]
    const int vr = tid >> 2, vc8 = (tid & 3) * 8;  // V: [64][32]

    for (int t0 = 0; t0 < SEQ; t0 += 32) {
        const size_t krow = qb + (size_t)(t0 + kr) * HDIM + kc8;
        const bf16x8 khv = *(const bf16x8*)&Khg[krow];
        const bf16x8 klv = *(const bf16x8*)&Klg[krow];
        const size_t vrow = vtb + (size_t)vr * SEQ + t0 + vc8;
        const bf16x8 vhv = *(const bf16x8*)&Vthg[vrow];
        const bf16x8 vlv = *(const bf16x8*)&Vtlg[vrow];
        __syncthreads();               // prev tile LDS reads done (fences Q @t0=0)
        *(bf16x8*)&Khs[kr][kc8] = khv;
        *(bf16x8*)&Kls[kr][kc8] = klv;
        *(bf16x8*)&Vhs[vr][vc8] = vhv;
        *(bf16x8*)&Vls[vr][vc8] = vlv;
        __syncthreads();

        // S = Q K^T (pre-scaled): 16q x 32t per wave
        f32x4 sj[2] = {fzero, fzero};
        #pragma unroll
        for (int ks = 0; ks < 2; ++ks) {
            const bf16x8 ah = *(const bf16x8*)&Qhs[16 * wv + col][8 * g + 32 * ks];
            const bf16x8 al = *(const bf16x8*)&Qls[16 * wv + col][8 * g + 32 * ks];
            #pragma unroll
            for (int j = 0; j < 2; ++j) {
                const bf16x8 bh = *(const bf16x8*)&Khs[16 * j + col][8 * g + 32 * ks];
                const bf16x8 bl = *(const bf16x8*)&Kls[16 * j + col][8 * g + 32 * ks];
                sj[j] = MFMA16(ah, bh, sj[j]);
                sj[j] = MFMA16(al, bh, sj[j]);
                sj[j] = MFMA16(ah, bl, sj[j]);
            }
        }

        // online softmax (16-lane group shares a row)
        #pragma unroll
        for (int r = 0; r < 4; ++r) {
            const float v0 = sj[0][r], v1 = sj[1][r];
            float rm = fmaxf(v0, v1);
            #pragma unroll
            for (int off = 8; off >= 1; off >>= 1)
                rm = fmaxf(rm, __shfl_xor(rm, off, 64));
            const float mn  = fmaxf(m_[r], rm);
            const float fsc = __expf(m_[r] - mn);
            const float p0  = __expf(v0 - mn);
            const float p1  = __expf(v1 - mn);
            float rs = p0 + p1;
            #pragma unroll
            for (int off = 8; off >= 1; off >>= 1)
                rs += __shfl_xor(rs, off, 64);
            m_[r] = mn;
            l_[r] = l_[r] * fsc + rs;
            #pragma unroll
            for (int df = 0; df < 4; ++df) O[df][r] *= fsc;
            const int prow = 16 * wv + 4 * g + r;
            Ps[prow][col]      = p0;
            Ps[prow][16 + col] = p1;
        }
        // within-wave LDS write->read (same wave's rows): in-order, no barrier

        // O += P V
        const float4 pa = *(const float4*)&Ps[16 * wv + col][8 * g];
        const float4 pb = *(const float4*)&Ps[16 * wv + col][8 * g + 4];
        const float pf[8] = {pa.x, pa.y, pa.z, pa.w, pb.x, pb.y, pb.z, pb.w};
        bf16x8 ph, pl;
        #pragma unroll
        for (int j = 0; j < 8; ++j) {
            unsigned hb, lb;
            split2(pf[j], hb, lb);
            ph[j] = (short)hb;
            pl[j] = (short)lb;
        }
        #pragma unroll
        for (int df = 0; df < 4; ++df) {
            const bf16x8 vh = *(const bf16x8*)&Vhs[16 * df + col][8 * g];
            const bf16x8 vl = *(const bf16x8*)&Vls[16 * df + col][8 * g];
            O[df] = MFMA16(ph, vh, O[df]);
            O[df] = MFMA16(pl, vh, O[df]);
            O[df] = MFMA16(ph, vl, O[df]);
        }
    }

    #pragma unroll
    for (int r = 0; r < 4; ++r) {
        const float inv = 1.0f / l_[r];
        const int q = q0 + 16 * wv + 4 * g + r;
        #pragma unroll
        for (int df = 0; df < 4; ++df)
            Yb[((size_t)nh * SEQ + q) * HDIM + 16 * df + col] = O[df][r] * inv;
    }
}

// ---------------------------------------------------------------------------
// proj2_k: out[m,e] = sum_k y[m,k]*Wp[e,k] + bp[e].
// y fp32 [nh][s][dk] split in-staging; Wp pre-split. Same 3-term core.
// ---------------------------------------------------------------------------
__global__ __launch_bounds__(256) void proj2_k(
    const float* __restrict__ Y,
    const short* __restrict__ Wps, const float* __restrict__ bp,
    float* __restrict__ out)
{
    __shared__ short smem[4 * 128 * GSB];
    short (*Ash)[GSB] = (short(*)[GSB])smem;
    short (*Asl)[GSB] = (short(*)[GSB])(smem + 128 * GSB);
    short (*Bsh)[GSB] = (short(*)[GSB])(smem + 2 * 128 * GSB);
    short (*Bsl)[GSB] = (short(*)[GSB])(smem + 3 * 128 * GSB);

    const int tid  = threadIdx.x;
    const int lane = tid & 63;
    const int wv   = tid >> 6;
    const int col  = lane & 15;
    const int g    = lane >> 4;
    const int wm   = wv & 1, we = wv >> 1;

    const int m0 = blockIdx.x * 128;
    const int e0 = blockIdx.y * 128;

    const int sr = tid >> 2, sc = (tid & 3) * 8;
    const int n  = m0 >> 11;
    const int s0 = m0 & (SEQ - 1);
    const short* Bw = Wps + (size_t)e0 * 2048;

    const f32x4 fzero = {0.f, 0.f, 0.f, 0.f};
    f32x4 acc[4][4];
    #pragma unroll
    for (int i = 0; i < 4; ++i)
        #pragma unroll
        for (int j = 0; j < 4; ++j) acc[i][j] = fzero;

    for (int kt = 0; kt < DMODEL; kt += 32) {
        const int h = (kt + sc) >> 6, dk = (kt + sc) & 63;   // 8-run within head
        float4 a0[2], a1[2];
        bf16x8 pbh[2], pbl[2];
        #pragma unroll
        for (int f = 0; f < 2; ++f) {
            const int s = s0 + sr + 64 * f;
            const float* ap = Y + ((size_t)(n * NHEAD + h) * SEQ + s) * HDIM + dk;
            a0[f] = *(const float4*)ap;
            a1[f] = *(const float4*)(ap + 4);
            const short* bpp = Bw + (size_t)(sr + 64 * f) * 2048 + kt + sc;
            pbh[f] = *(const bf16x8*)bpp;
            pbl[f] = *(const bf16x8*)(bpp + 1024);
        }
        __syncthreads();
        #pragma unroll
        for (int f = 0; f < 2; ++f) {
            split_store8(a0[f], a1[f], &Ash[sr + 64 * f][sc], &Asl[sr + 64 * f][sc]);
            *(bf16x8*)&Bsh[sr + 64 * f][sc] = pbh[f];
            *(bf16x8*)&Bsl[sr + 64 * f][sc] = pbl[f];
        }
        __syncthreads();

        bf16x8 fah[4], fal[4], fbh[4], fbl[4];
        #pragma unroll
        for (int i = 0; i < 4; ++i) {
            fah[i] = *(const bf16x8*)&Ash[64 * wm + 16 * i + col][8 * g];
            fal[i] = *(const bf16x8*)&Asl[64 * wm + 16 * i + col][8 * g];
        }
        #pragma unroll
        for (int j = 0; j < 4; ++j) {
            fbh[j] = *(const bf16x8*)&Bsh[64 * we + 16 * j + col][8 * g];
            fbl[j] = *(const bf16x8*)&Bsl[64 * we + 16 * j + col][8 * g];
        }
        #pragma unroll
        for (int i = 0; i < 4; ++i)
            #pragma unroll
            for (int j = 0; j < 4; ++j) {
                acc[i][j] = MFMA16(fah[i], fbh[j], acc[i][j]);
                acc[i][j] = MFMA16(fal[i], fbh[j], acc[i][j]);
                acc[i][j] = MFMA16(fah[i], fbl[j], acc[i][j]);
            }
    }

    #pragma unroll
    for (int i = 0; i < 4; ++i)
        #pragma unroll
        for (int j = 0; j < 4; ++j) {
            const int e = e0 + 64 * we + 16 * j + col;
            const float bb = bp[e];
            #pragma unroll
            for (int r = 0; r < 4; ++r) {
                const int m = m0 + 64 * wm + 16 * i + 4 * g + r;
                out[(size_t)m * DMODEL + e] = acc[i][j][r] + bb;
            }
        }
}

// ===========================================================================
// ===================== FALLBACK PATH (round-2, 96 MiB) =====================
// ===========================================================================

__global__ __launch_bounds__(256) void qkv_gemm_k(
    const float* __restrict__ x,
    const float* __restrict__ Wq, const float* __restrict__ bq,
    const float* __restrict__ Wk, const float* __restrict__ bk,
    const float* __restrict__ Wv, const float* __restrict__ bv,
    float* __restrict__ Qb,
    short* __restrict__ Khg, short* __restrict__ Klg,
    short* __restrict__ Vthg, short* __restrict__ Vtlg)
{
    __shared__ short Ah[64][GSB], Al[64][GSB];
    __shared__ short Bh[64][GSB], Bl[64][GSB];
    __shared__ short Th[64][TSB], Tl[64][TSB];

    const int tid  = threadIdx.x;
    const int lane = tid & 63;
    const int wv   = tid >> 6;
    const int col  = lane & 15;
    const int g    = lane >> 4;
    const int wm   = wv & 1, we = wv >> 1;

    const int m0  = blockIdx.x * 64;
    const int by  = blockIdx.y;
    const int mat = by >> 4;
    const int hh  = by & 15;

    const float* W    = (mat == 0) ? Wq : (mat == 1) ? Wk : Wv;
    const float* bias = (mat == 0) ? bq : (mat == 1) ? bk : bv;

    const int lrow = tid >> 2;
    const int lc   = (tid & 3) * 8;
    const float* Ap = x + (size_t)(m0 + lrow) * DMODEL + lc;
    const float* Bp = W + (size_t)(hh * HDIM + lrow) * DMODEL + lc;

    const f32x4 fzero = {0.f, 0.f, 0.f, 0.f};
    f32x4 acc[2][2];
    #pragma unroll
    for (int i = 0; i < 2; ++i)
        #pragma unroll
        for (int j = 0; j < 2; ++j) acc[i][j] = fzero;

    for (int kt = 0; kt < DMODEL; kt += 32) {
        const float4 a0 = *(const float4*)(Ap + kt);
        const float4 a1 = *(const float4*)(Ap + kt + 4);
        const float4 b0 = *(const float4*)(Bp + kt);
        const float4 b1 = *(const float4*)(Bp + kt + 4);
        __syncthreads();
        split_store8(a0, a1, &Ah[lrow][lc], &Al[lrow][lc]);
        split_store8(b0, b1, &Bh[lrow][lc], &Bl[lrow][lc]);
        __syncthreads();

        bf16x8 ah[2], al[2], bhf[2], blf[2];
        #pragma unroll
        for (int f = 0; f < 2; ++f) {
            const int ar = 32 * wm + 16 * f + col;
            ah[f] = *(const bf16x8*)&Ah[ar][8 * g];
            al[f] = *(const bf16x8*)&Al[ar][8 * g];
            const int br = 32 * we + 16 * f + col;
            bhf[f] = *(const bf16x8*)&Bh[br][8 * g];
            blf[f] = *(const bf16x8*)&Bl[br][8 * g];
        }
        #pragma unroll
        for (int i = 0; i < 2; ++i)
            #pragma unroll
            for (int j = 0; j < 2; ++j) {
                acc[i][j] = MFMA16(ah[i], bhf[j], acc[i][j]);
                acc[i][j] = MFMA16(al[i], bhf[j], acc[i][j]);
                acc[i][j] = MFMA16(ah[i], blf[j], acc[i][j]);
            }
    }

    const int nb = m0 >> 11;
    const int s0 = m0 & (SEQ - 1);
    const int nh = nb * NHEAD + hh;

    if (mat == 0) {
        #pragma unroll
        for (int i = 0; i < 2; ++i)
            #pragma unroll
            for (int j = 0; j < 2; ++j) {
                const int dk = 32 * we + 16 * j + col;
                const float bb = bias[hh * HDIM + dk];
                #pragma unroll
                for (int r = 0; r < 4; ++r) {
                    const int s = s0 + 32 * wm + 16 * i + 4 * g + r;
                    Qb[((size_t)nh * SEQ + s) * HDIM + dk] = acc[i][j][r] + bb;
                }
            }
    } else if (mat == 1) {
        #pragma unroll
        for (int i = 0; i < 2; ++i)
            #pragma unroll
            for (int j = 0; j < 2; ++j) {
                const int dk = 32 * we + 16 * j + col;
                const float bb = bias[hh * HDIM + dk];
                #pragma unroll
                for (int r = 0; r < 4; ++r) {
                    const int s = s0 + 32 * wm + 16 * i + 4 * g + r;
                    unsigned hb, lb;
                    split2(acc[i][j][r] + bb, hb, lb);
                    const size_t idx = ((size_t)nh * SEQ + s) * HDIM + dk;
                    Khg[idx] = (short)hb;
                    Klg[idx] = (short)lb;
                }
            }
    } else {
        #pragma unroll
        for (int i = 0; i < 2; ++i)
            #pragma unroll
            for (int j = 0; j < 2; ++j) {
                const int dk = 32 * we + 16 * j + col;
                const float bb = bias[hh * HDIM + dk];
                #pragma unroll
                for (int r = 0; r < 4; ++r) {
                    const int sl = 32 * wm + 16 * i + 4 * g + r;
                    unsigned hb, lb;
                    split2(acc[i][j][r] + bb, hb, lb);
                    Th[dk][sl] = (short)hb;
                    Tl[dk][sl] = (short)lb;
                }
            }
        __syncthreads();
        const int r2 = tid >> 2;
        const int c2 = (tid & 3) * 16;
        const size_t ob = ((size_t)nh * HDIM + r2) * SEQ + s0 + c2;
        *(bf16x8*)&Vthg[ob]     = *(const bf16x8*)&Th[r2][c2];
        *(bf16x8*)&Vthg[ob + 8] = *(const bf16x8*)&Th[r2][c2 + 8];
        *(bf16x8*)&Vtlg[ob]     = *(const bf16x8*)&Tl[r2][c2];
        *(bf16x8*)&Vtlg[ob + 8] = *(const bf16x8*)&Tl[r2][c2 + 8];
    }
}

__global__ __launch_bounds__(256) void attn_k(
    const float* __restrict__ Qb,
    const short* __restrict__ Khg, const short* __restrict__ Klg,
    const short* __restrict__ Vthg, const short* __restrict__ Vtlg,
    float* __restrict__ Yb)
{
    __shared__ short Qh[64][TSB], Ql[64][TSB];
    __shared__ short Khs[32][TSB], Kls[32][TSB];
    __shared__ short Vhs[64][GSB], Vls[64][GSB];
    __shared__ float Ps[64][36];

    const int tid  = threadIdx.x;
    const int lane = tid & 63;
    const int wv   = tid >> 6;
    const int col  = lane & 15;
    const int g    = lane >> 4;
    const int q0   = blockIdx.x * 64;
    const int nh   = blockIdx.y;

    const float* Qp  = Qb + (size_t)nh * SEQ * HDIM;
    const size_t kvb = (size_t)nh * SEQ * HDIM;
    const size_t vtb = (size_t)nh * HDIM * SEQ;

    {
        const int rq = tid >> 3;
        const int kc = (tid & 7) * 8;
        #pragma unroll
        for (int half = 0; half < 2; ++half) {
            const int rr = half * 32 + rq;
            const float4 a0 = *(const float4*)&Qp[(size_t)(q0 + rr) * HDIM + kc];
            const float4 a1 = *(const float4*)&Qp[(size_t)(q0 + rr) * HDIM + kc + 4];
            const float f[8] = {a0.x * SCALE, a0.y * SCALE, a0.z * SCALE, a0.w * SCALE,
                                a1.x * SCALE, a1.y * SCALE, a1.z * SCALE, a1.w * SCALE};
            bf16x8 hv, lv;
            #pragma unroll
            for (int j = 0; j < 8; ++j) {
                unsigned hb, lb;
                split2(f[j], hb, lb);
                hv[j] = (short)hb;
                lv[j] = (short)lb;
            }
            *(bf16x8*)&Qh[rr][kc] = hv;
            *(bf16x8*)&Ql[rr][kc] = lv;
        }
    }

    const f32x4 fzero = {0.f, 0.f, 0.f, 0.f};
    f32x4 O[4];
    float m_[4], l_[4];
    #pragma unroll
    for (int d = 0; d < 4; ++d) O[d] = fzero;
    #pragma unroll
    for (int r = 0; r < 4; ++r) { m_[r] = -1e30f; l_[r] = 0.f; }

    const int kr = tid >> 3, kc8 = (tid & 7) * 8;
    const int vr = tid >> 2, vc8 = (tid & 3) * 8;

    for (int t0 = 0; t0 < SEQ; t0 += 32) {
        const size_t krow = kvb + (size_t)(t0 + kr) * HDIM + kc8;
        const bf16x8 khv = *(const bf16x8*)&Khg[krow];
        const bf16x8 klv = *(const bf16x8*)&Klg[krow];
        const size_t vrow = vtb + (size_t)vr * SEQ + t0 + vc8;
        const bf16x8 vhv = *(const bf16x8*)&Vthg[vrow];
        const bf16x8 vlv = *(const bf16x8*)&Vtlg[vrow];
        __syncthreads();
        *(bf16x8*)&Khs[kr][kc8] = khv;
        *(bf16x8*)&Kls[kr][kc8] = klv;
        *(bf16x8*)&Vhs[vr][vc8] = vhv;
        *(bf16x8*)&Vls[vr][vc8] = vlv;
        __syncthreads();

        f32x4 sj[2] = {fzero, fzero};
        #pragma unroll
        for (int ks = 0; ks < 2; ++ks) {
            const bf16x8 ah = *(const bf16x8*)&Qh[16 * wv + col][8 * g + 32 * ks];
            const bf16x8 al = *(const bf16x8*)&Ql[16 * wv + col][8 * g + 32 * ks];
            #pragma unroll
            for (int j = 0; j < 2; ++j) {
                const bf16x8 bh = *(const bf16x8*)&Khs[16 * j + col][8 * g + 32 * ks];
                const bf16x8 bl = *(const bf16x8*)&Kls[16 * j + col][8 * g + 32 * ks];
                sj[j] = MFMA16(ah, bh, sj[j]);
                sj[j] = MFMA16(al, bh, sj[j]);
                sj[j] = MFMA16(ah, bl, sj[j]);
            }
        }

        #pragma unroll
        for (int r = 0; r < 4; ++r) {
            const float v0 = sj[0][r], v1 = sj[1][r];
            float rm = fmaxf(v0, v1);
            #pragma unroll
            for (int off = 8; off >= 1; off >>= 1)
                rm = fmaxf(rm, __shfl_xor(rm, off, 64));
            const float mn  = fmaxf(m_[r], rm);
            const float fsc = __expf(m_[r] - mn);
            const float p0  = __expf(v0 - mn);
            const float p1  = __expf(v1 - mn);
            float rs = p0 + p1;
            #pragma unroll
            for (int off = 8; off >= 1; off >>= 1)
                rs += __shfl_xor(rs, off, 64);
            m_[r] = mn;
            l_[r] = l_[r] * fsc + rs;
            #pragma unroll
            for (int df = 0; df < 4; ++df) O[df][r] *= fsc;
            const int prow = 16 * wv + 4 * g + r;
            Ps[prow][col]      = p0;
            Ps[prow][16 + col] = p1;
        }

        const float4 pa = *(const float4*)&Ps[16 * wv + col][8 * g];
        const float4 pb = *(const float4*)&Ps[16 * wv + col][8 * g + 4];
        const float pf[8] = {pa.x, pa.y, pa.z, pa.w, pb.x, pb.y, pb.z, pb.w};
        bf16x8 ph, pl;
        #pragma unroll
        for (int j = 0; j < 8; ++j) {
            unsigned hb, lb;
            split2(pf[j], hb, lb);
            ph[j] = (short)hb;
            pl[j] = (short)lb;
        }
        #pragma unroll
        for (int df = 0; df < 4; ++df) {
            const bf16x8 vh = *(const bf16x8*)&Vhs[16 * df + col][8 * g];
            const bf16x8 vl = *(const bf16x8*)&Vls[16 * df + col][8 * g];
            O[df] = MFMA16(ph, vh, O[df]);
            O[df] = MFMA16(pl, vh, O[df]);
            O[df] = MFMA16(ph, vl, O[df]);
        }
    }

    #pragma unroll
    for (int r = 0; r < 4; ++r) {
        const float inv = 1.0f / l_[r];
        const int q = q0 + 16 * wv + 4 * g + r;
        #pragma unroll
        for (int df = 0; df < 4; ++df)
            Yb[((size_t)nh * SEQ + q) * HDIM + 16 * df + col] = O[df][r] * inv;
    }
}

__global__ __launch_bounds__(256) void proj_gemm_k(
    const float* __restrict__ Y,
    const float* __restrict__ Wp, const float* __restrict__ bp,
    float* __restrict__ out)
{
    __shared__ short Ah[64][GSB], Al[64][GSB];
    __shared__ short Bh[64][GSB], Bl[64][GSB];

    const int tid  = threadIdx.x;
    const int lane = tid & 63;
    const int wv   = tid >> 6;
    const int col  = lane & 15;
    const int g    = lane >> 4;
    const int wm   = wv & 1, we = wv >> 1;

    const int m0 = blockIdx.x * 64;
    const int e0 = blockIdx.y * 64;

    const int lrow = tid >> 2;
    const int lc   = (tid & 3) * 8;

    const int nb = m0 >> 11;
    const int s0 = m0 & (SEQ - 1);
    const float* Bp = Wp + (size_t)(e0 + lrow) * DMODEL + lc;

    const f32x4 fzero = {0.f, 0.f, 0.f, 0.f};
    f32x4 acc[2][2];
    #pragma unroll
    for (int i = 0; i < 2; ++i)
        #pragma unroll
        for (int j = 0; j < 2; ++j) acc[i][j] = fzero;

    for (int kt = 0; kt < DMODEL; kt += 32) {
        const int k  = kt + lc;
        const int hh = k >> 6, dk = k & 63;
        const size_t ai = ((size_t)(nb * NHEAD + hh) * SEQ + s0 + lrow) * HDIM + dk;
        const float4 a0 = *(const float4*)&Y[ai];
        const float4 a1 = *(const float4*)&Y[ai + 4];
        const float4 b0 = *(const float4*)(Bp + kt);
        const float4 b1 = *(const float4*)(Bp + kt + 4);
        __syncthreads();
        split_store8(a0, a1, &Ah[lrow][lc], &Al[lrow][lc]);
        split_store8(b0, b1, &Bh[lrow][lc], &Bl[lrow][lc]);
        __syncthreads();

        bf16x8 ah[2], al[2], bhf[2], blf[2];
        #pragma unroll
        for (int f = 0; f < 2; ++f) {
            const int ar = 32 * wm + 16 * f + col;
            ah[f] = *(const bf16x8*)&Ah[ar][8 * g];
            al[f] = *(const bf16x8*)&Al[ar][8 * g];
            const int br = 32 * we + 16 * f + col;
            bhf[f] = *(const bf16x8*)&Bh[br][8 * g];
            blf[f] = *(const bf16x8*)&Bl[br][8 * g];
        }
        #pragma unroll
        for (int i = 0; i < 2; ++i)
            #pragma unroll
            for (int j = 0; j < 2; ++j) {
                acc[i][j] = MFMA16(ah[i], bhf[j], acc[i][j]);
                acc[i][j] = MFMA16(al[i], bhf[j], acc[i][j]);
                acc[i][j] = MFMA16(ah[i], blf[j], acc[i][j]);
            }
    }

    #pragma unroll
    for (int i = 0; i < 2; ++i)
        #pragma unroll
        for (int j = 0; j < 2; ++j) {
            const int e = e0 + 32 * we + 16 * j + col;
            const float bb = bp[e];
            #pragma unroll
            for (int r = 0; r < 4; ++r) {
                const int m = m0 + 32 * wm + 16 * i + 4 * g + r;
                out[(size_t)m * DMODEL + e] = acc[i][j][r] + bb;
            }
        }
}

// ---------------------------------------------------------------------------
extern "C" void kernel_launch(void* const* d_in, const int* in_sizes, int n_in,
                              void* d_out, int out_size, void* d_ws, size_t ws_size,
                              hipStream_t stream) {
    (void)in_sizes; (void)n_in; (void)out_size;
    const float* x  = (const float*)d_in[0];
    const float* Wq = (const float*)d_in[1];
    const float* bq = (const float*)d_in[2];
    const float* Wk = (const float*)d_in[3];
    const float* bk = (const float*)d_in[4];
    const float* Wv = (const float*)d_in[5];
    const float* bv = (const float*)d_in[6];
    const float* Wp = (const float*)d_in[7];
    const float* bp = (const float*)d_in[8];
    float* out = (float*)d_out;

    const size_t MiB = 1048576;
    char* wsb = (char*)d_ws;

    if (ws_size >= 144 * MiB) {
        // ---- FAST PATH ----
        // [0,16): Wqs/Wks/Wvs/Wps (4 MiB each) ; [16,48): Qh,Ql ; [48,80): Kh,Kl
        // [80,112): Vth,Vtl ; [112,144): y fp32
        short* Wqs = (short*)(wsb);
        short* Wks = (short*)(wsb + 4  * MiB);
        short* Wvs = (short*)(wsb + 8  * MiB);
        short* Wps = (short*)(wsb + 12 * MiB);
        short* Qh  = (short*)(wsb + 16 * MiB);
        short* Ql  = (short*)(wsb + 32 * MiB);
        short* Kh  = (short*)(wsb + 48 * MiB);
        short* Kl  = (short*)(wsb + 64 * MiB);
        short* Vth = (short*)(wsb + 80 * MiB);
        short* Vtl = (short*)(wsb + 96 * MiB);
        float* Yb  = (float*)(wsb + 112 * MiB);

        presplit_w_k<<<dim3(512, 4), 256, 0, stream>>>(
            Wq, Wk, Wv, Wp, Wqs, Wks, Wvs, Wps);
        qkv2_k<<<dim3(8192 / 128, 24), 256, 0, stream>>>(
            x, Wqs, Wks, Wvs, bq, bk, bv, Qh, Ql, Kh, Kl, Vth, Vtl);
        attn2_k<<<dim3(SEQ / 64, NH_TOT), 256, 0, stream>>>(
            Qh, Ql, Kh, Kl, Vth, Vtl, Yb);
        proj2_k<<<dim3(8192 / 128, DMODEL / 128), 256, 0, stream>>>(
            Yb, Wps, bp, out);
    } else {
        // ---- FALLBACK (round-2 pipeline, 96 MiB) ----
        float* Qb   = (float*)(wsb);
        short* Khg  = (short*)(wsb + 32 * MiB);
        short* Klg  = (short*)(wsb + 48 * MiB);
        short* Vthg = (short*)(wsb + 64 * MiB);
        short* Vtlg = (short*)(wsb + 80 * MiB);

        qkv_gemm_k<<<dim3(8192 / 64, 48), 256, 0, stream>>>(
            x, Wq, bq, Wk, bk, Wv, bv, Qb, Khg, Klg, Vthg, Vtlg);
        attn_k<<<dim3(SEQ / 64, NH_TOT), 256, 0, stream>>>(
            Qb, Khg, Klg, Vthg, Vtlg, Qb);
        proj_gemm_k<<<dim3(8192 / 64, DMODEL / 64), 256, 0, stream>>>(
            Qb, Wp, bp, out);
    }
}

// Round 11
// 449.157 us; speedup vs baseline: 1.9751x; 1.9751x over previous
//
#include <hip/hip_runtime.h>
#include <hip/hip_bf16.h>
#include <math.h>

// Problem constants (N=4, S=2048, D=1024, H=16, DK=64)
#define SEQ    2048
#define DMODEL 1024
#define NHEAD  16
#define HDIM   64
#define NH_TOT 64            // N * NHEAD
#define SCALE  0.125f        // 1/sqrt(64)

typedef __attribute__((ext_vector_type(8))) _Float16 f16x8;  // 8 f16 = 4 VGPRs
typedef __attribute__((ext_vector_type(4))) float    f32x4;

#define MFMA16(a, b, c) __builtin_amdgcn_mfma_f32_16x16x32_f16((a), (b), (c), 0, 0, 0)

__device__ __forceinline__ f16x8 cvt8(const float4& a0, const float4& a1) {
    f16x8 v;
    v[0] = (_Float16)a0.x; v[1] = (_Float16)a0.y;
    v[2] = (_Float16)a0.z; v[3] = (_Float16)a0.w;
    v[4] = (_Float16)a1.x; v[5] = (_Float16)a1.y;
    v[6] = (_Float16)a1.z; v[7] = (_Float16)a1.w;
    return v;
}

#define GSB 40   // LDS row stride (elems) for 32-wide k tiles: 80 B rows
#define TSB 72   // LDS row stride (elems) for 64-wide tiles: 144 B rows

// ---------------------------------------------------------------------------
// cvtw_k: W fp32 [1024][1024] -> f16 [1024][1024]; blockIdx.y picks matrix.
// ---------------------------------------------------------------------------
__global__ __launch_bounds__(256) void cvtw_k(
    const float* __restrict__ Wq, const float* __restrict__ Wk,
    const float* __restrict__ Wv, const float* __restrict__ Wp,
    _Float16* __restrict__ Oq, _Float16* __restrict__ Ok,
    _Float16* __restrict__ Ov, _Float16* __restrict__ Op)
{
    const int t = blockIdx.y;
    const float*    s = (t == 0) ? Wq : (t == 1) ? Wk : (t == 2) ? Wv : Wp;
    _Float16*       d = (t == 0) ? Oq : (t == 1) ? Ok : (t == 2) ? Ov : Op;
    const int i = (blockIdx.x * 256 + threadIdx.x) * 8;
    *(f16x8*)&d[i] = cvt8(*(const float4*)(s + i), *(const float4*)(s + i + 4));
}

// ---------------------------------------------------------------------------
// qkv3_k: f16 GEMM.  C[m,e] = sum_k x[m,k]*W[e,k] + b[e]
// Block 128m x 128e, BK=32, 4 waves (2m x 2e), per-wave 64x64 (4x4 frags),
// 16 MFMA + 8 ds_read_b128 per k-step per wave.
// Epilogue: mat0 -> Q f16 [nh][s][dk] pre-scaled by SCALE;
//           mat1 -> K f16 [nh][s][dk];
//           mat2 -> V f16 TRANSPOSED [nh][dk][s] via in-LDS 128x128 transpose.
// ---------------------------------------------------------------------------
__global__ __launch_bounds__(256) void qkv3_k(
    const float* __restrict__ x,
    const _Float16* __restrict__ Wqs, const _Float16* __restrict__ Wks,
    const _Float16* __restrict__ Wvs,
    const float* __restrict__ bq, const float* __restrict__ bk,
    const float* __restrict__ bv,
    _Float16* __restrict__ Qg, _Float16* __restrict__ Kg,
    _Float16* __restrict__ Vtg)
{
    __shared__ _Float16 smem[128 * 136];           // 34816 B (union: A/B | T)
    _Float16 (*As)[GSB] = (_Float16(*)[GSB])smem;  // [128][40]
    _Float16 (*Bs)[GSB] = (_Float16(*)[GSB])(smem + 128 * GSB);

    const int tid  = threadIdx.x;
    const int lane = tid & 63;
    const int wv   = tid >> 6;
    const int col  = lane & 15;
    const int g    = lane >> 4;
    const int wm   = wv & 1, we = wv >> 1;

    const int m0  = blockIdx.x * 128;
    const int by  = blockIdx.y;                    // 0..23
    const int mat = by >> 3;                       // 0=Q 1=K 2=V
    const int e0  = (by & 7) * 128;

    const _Float16* Ws = (mat == 0) ? Wqs : (mat == 1) ? Wks : Wvs;
    const float* bias  = (mat == 0) ? bq  : (mat == 1) ? bk  : bv;

    const int sr = tid >> 2, sc = (tid & 3) * 8;   // staging: 4 thr/row
    const float*    Ax = x  + (size_t)m0 * DMODEL;
    const _Float16* Bw = Ws + (size_t)e0 * DMODEL;

    const f32x4 fzero = {0.f, 0.f, 0.f, 0.f};
    f32x4 acc[4][4];
    #pragma unroll
    for (int i = 0; i < 4; ++i)
        #pragma unroll
        for (int j = 0; j < 4; ++j) acc[i][j] = fzero;

    for (int kt = 0; kt < DMODEL; kt += 32) {
        float4 a0[2], a1[2];
        f16x8 pb[2];
        #pragma unroll
        for (int f = 0; f < 2; ++f) {
            const float* ap = Ax + (size_t)(sr + 64 * f) * DMODEL + kt + sc;
            a0[f] = *(const float4*)ap;
            a1[f] = *(const float4*)(ap + 4);
            pb[f] = *(const f16x8*)(Bw + (size_t)(sr + 64 * f) * DMODEL + kt + sc);
        }
        __syncthreads();                           // prev iter frag reads done
        #pragma unroll
        for (int f = 0; f < 2; ++f) {
            *(f16x8*)&As[sr + 64 * f][sc] = cvt8(a0[f], a1[f]);
            *(f16x8*)&Bs[sr + 64 * f][sc] = pb[f];
        }
        __syncthreads();

        f16x8 fa[4], fb[4];
        #pragma unroll
        for (int i = 0; i < 4; ++i)
            fa[i] = *(const f16x8*)&As[64 * wm + 16 * i + col][8 * g];
        #pragma unroll
        for (int j = 0; j < 4; ++j)
            fb[j] = *(const f16x8*)&Bs[64 * we + 16 * j + col][8 * g];
        #pragma unroll
        for (int i = 0; i < 4; ++i)
            #pragma unroll
            for (int j = 0; j < 4; ++j)
                acc[i][j] = MFMA16(fa[i], fb[j], acc[i][j]);
    }

    const int n  = m0 >> 11;                       // batch
    const int s0 = m0 & (SEQ - 1);

    if (mat <= 1) {
        _Float16* Dg = (mat == 0) ? Qg : Kg;
        const float sc2 = (mat == 0) ? SCALE : 1.0f;
        #pragma unroll
        for (int i = 0; i < 4; ++i)
            #pragma unroll
            for (int j = 0; j < 4; ++j) {
                const int em = e0 + 64 * we + 16 * j + col;   // 0..1023
                const int h = em >> 6, dk = em & 63;
                const int nh = n * NHEAD + h;
                const float bb = bias[em];
                #pragma unroll
                for (int r = 0; r < 4; ++r) {
                    const int s = s0 + 64 * wm + 16 * i + 4 * g + r;
                    Dg[((size_t)nh * SEQ + s) * HDIM + dk] =
                        (_Float16)((acc[i][j][r] + bb) * sc2);
                }
            }
    } else {
        // V: transpose 128x128 through LDS, write [nh][dk][s] coalesced
        _Float16 (*T)[136] = (_Float16(*)[136])smem;
        __syncthreads();                           // last frag reads done
        #pragma unroll
        for (int i = 0; i < 4; ++i)
            #pragma unroll
            for (int j = 0; j < 4; ++j) {
                const int em  = e0 + 64 * we + 16 * j + col;
                const int dkl = 64 * we + 16 * j + col;       // local 0..127
                const float bb = bias[em];
                #pragma unroll
                for (int r = 0; r < 4; ++r) {
                    const int sl = 64 * wm + 16 * i + 4 * g + r;
                    T[dkl][sl] = (_Float16)(acc[i][j][r] + bb);
                }
            }
        __syncthreads();
        const int tr  = tid >> 1;                  // local dk row 0..127
        const int tc0 = (tid & 1) * 64;
        const int em  = e0 + tr;
        const int h = em >> 6, dk = em & 63;
        const int nh = n * NHEAD + h;
        _Float16* dst = Vtg + ((size_t)nh * HDIM + dk) * SEQ + s0 + tc0;
        #pragma unroll
        for (int f = 0; f < 8; ++f)
            *(f16x8*)&dst[8 * f] = *(const f16x8*)&T[tr][tc0 + 8 * f];
    }
}

// ---------------------------------------------------------------------------
// attn3_k: flash attention, f16 MFMA, fp32 online softmax.
// Block: 128 q-rows x one nh (grid 16 x 64). 4 waves; wave owns 32 q-rows
// (2 x 16-row subtiles). KV tiles of 64. Q hoisted to registers. P tile
// round-trips LDS as f16 (wave-private rows, no barrier). y written f16.
// ---------------------------------------------------------------------------
__global__ __launch_bounds__(256) void attn3_k(
    const _Float16* __restrict__ Qg, const _Float16* __restrict__ Kg,
    const _Float16* __restrict__ Vtg, _Float16* __restrict__ Yg)
{
    __shared__ _Float16 Ks[64][TSB];     // [t][dk]
    __shared__ _Float16 Vs[64][TSB];     // [dk][t]
    __shared__ _Float16 Pb[128][TSB];    // [q][t]

    const int tid  = threadIdx.x;
    const int lane = tid & 63;
    const int wv   = tid >> 6;
    const int col  = lane & 15;
    const int g    = lane >> 4;
    const int q0   = blockIdx.x * 128;
    const int nh   = blockIdx.y;

    const size_t qb  = (size_t)nh * SEQ * HDIM;
    const size_t vtb = (size_t)nh * HDIM * SEQ;

    // ---- hoist Q fragments (pre-scaled f16): rows 32wv+16qi+col ----
    f16x8 qreg[2][2];
    #pragma unroll
    for (int qi = 0; qi < 2; ++qi)
        #pragma unroll
        for (int ks = 0; ks < 2; ++ks)
            qreg[qi][ks] = *(const f16x8*)
                &Qg[qb + (size_t)(q0 + 32 * wv + 16 * qi + col) * HDIM + 32 * ks + 8 * g];

    const f32x4 fzero = {0.f, 0.f, 0.f, 0.f};
    f32x4 O[2][4];
    float m_[2][4], l_[2][4];
    #pragma unroll
    for (int qi = 0; qi < 2; ++qi) {
        #pragma unroll
        for (int df = 0; df < 4; ++df) O[qi][df] = fzero;
        #pragma unroll
        for (int r = 0; r < 4; ++r) { m_[qi][r] = -1e30f; l_[qi][r] = 0.f; }
    }

    const int kr = tid >> 2, kc = (tid & 3) * 16;  // staging: [64][64], 4 thr/row

    for (int t0 = 0; t0 < SEQ; t0 += 64) {
        const size_t ko = qb  + (size_t)(t0 + kr) * HDIM + kc;
        const size_t vo = vtb + (size_t)kr * SEQ + t0 + kc;
        const f16x8 k0 = *(const f16x8*)&Kg[ko];
        const f16x8 k1 = *(const f16x8*)&Kg[ko + 8];
        const f16x8 v0 = *(const f16x8*)&Vtg[vo];
        const f16x8 v1 = *(const f16x8*)&Vtg[vo + 8];
        __syncthreads();                 // prev tile's LDS reads done
        *(f16x8*)&Ks[kr][kc]     = k0;
        *(f16x8*)&Ks[kr][kc + 8] = k1;
        *(f16x8*)&Vs[kr][kc]     = v0;
        *(f16x8*)&Vs[kr][kc + 8] = v1;
        __syncthreads();

        // ---- S = Q K^T : 32q x 64t per wave (B-frags shared across qi) ----
        f16x8 bh[4][2];
        #pragma unroll
        for (int j = 0; j < 4; ++j)
            #pragma unroll
            for (int ks = 0; ks < 2; ++ks)
                bh[j][ks] = *(const f16x8*)&Ks[16 * j + col][32 * ks + 8 * g];

        f32x4 sj[2][4];
        #pragma unroll
        for (int qi = 0; qi < 2; ++qi)
            #pragma unroll
            for (int j = 0; j < 4; ++j) {
                sj[qi][j] = fzero;
                #pragma unroll
                for (int ks = 0; ks < 2; ++ks)
                    sj[qi][j] = MFMA16(qreg[qi][ks], bh[j][ks], sj[qi][j]);
            }

        // ---- online softmax (16-lane group shares a row) + P -> LDS f16 ----
        #pragma unroll
        for (int qi = 0; qi < 2; ++qi)
            #pragma unroll
            for (int r = 0; r < 4; ++r) {
                float v0_ = sj[qi][0][r], v1_ = sj[qi][1][r];
                float v2_ = sj[qi][2][r], v3_ = sj[qi][3][r];
                float rm = fmaxf(fmaxf(v0_, v1_), fmaxf(v2_, v3_));
                #pragma unroll
                for (int off = 8; off >= 1; off >>= 1)
                    rm = fmaxf(rm, __shfl_xor(rm, off, 64));
                const float mn  = fmaxf(m_[qi][r], rm);
                const float fsc = __expf(m_[qi][r] - mn);
                const float p0 = __expf(v0_ - mn);
                const float p1 = __expf(v1_ - mn);
                const float p2 = __expf(v2_ - mn);
                const float p3 = __expf(v3_ - mn);
                float rs = (p0 + p1) + (p2 + p3);
                #pragma unroll
                for (int off = 8; off >= 1; off >>= 1)
                    rs += __shfl_xor(rs, off, 64);
                m_[qi][r] = mn;
                l_[qi][r] = l_[qi][r] * fsc + rs;
                #pragma unroll
                for (int df = 0; df < 4; ++df) O[qi][df][r] *= fsc;
                const int prow = 32 * wv + 16 * qi + 4 * g + r;
                Pb[prow][col]      = (_Float16)p0;
                Pb[prow][16 + col] = (_Float16)p1;
                Pb[prow][32 + col] = (_Float16)p2;
                Pb[prow][48 + col] = (_Float16)p3;
            }
        // wave-private P rows, same-wave write->read: in-order, no barrier

        // ---- O += P V ----
        f16x8 vb[4][2];
        #pragma unroll
        for (int df = 0; df < 4; ++df)
            #pragma unroll
            for (int ks = 0; ks < 2; ++ks)
                vb[df][ks] = *(const f16x8*)&Vs[16 * df + col][32 * ks + 8 * g];
        #pragma unroll
        for (int qi = 0; qi < 2; ++qi) {
            f16x8 pa[2];
            #pragma unroll
            for (int ks = 0; ks < 2; ++ks)
                pa[ks] = *(const f16x8*)&Pb[32 * wv + 16 * qi + col][32 * ks + 8 * g];
            #pragma unroll
            for (int df = 0; df < 4; ++df)
                #pragma unroll
                for (int ks = 0; ks < 2; ++ks)
                    O[qi][df] = MFMA16(pa[ks], vb[df][ks], O[qi][df]);
        }
    }

    // ---- epilogue: y = O / l, f16 [nh][s][dk] ----
    #pragma unroll
    for (int qi = 0; qi < 2; ++qi)
        #pragma unroll
        for (int r = 0; r < 4; ++r) {
            const float inv = 1.0f / l_[qi][r];
            const int q = q0 + 32 * wv + 16 * qi + 4 * g + r;
            #pragma unroll
            for (int df = 0; df < 4; ++df)
                Yg[qb + (size_t)q * HDIM + 16 * df + col] =
                    (_Float16)(O[qi][df][r] * inv);
        }
}

// ---------------------------------------------------------------------------
// proj3_k: out[m,e] = sum_k y[m,k]*Wp[e,k] + bp[e].
// y f16 [nh][s][dk] (head-aware reads), Wp f16. fp32 out.
// ---------------------------------------------------------------------------
__global__ __launch_bounds__(256) void proj3_k(
    const _Float16* __restrict__ Yg,
    const _Float16* __restrict__ Wps, const float* __restrict__ bp,
    float* __restrict__ out)
{
    __shared__ _Float16 smem[2 * 128 * GSB];
    _Float16 (*As)[GSB] = (_Float16(*)[GSB])smem;
    _Float16 (*Bs)[GSB] = (_Float16(*)[GSB])(smem + 128 * GSB);

    const int tid  = threadIdx.x;
    const int lane = tid & 63;
    const int wv   = tid >> 6;
    const int col  = lane & 15;
    const int g    = lane >> 4;
    const int wm   = wv & 1, we = wv >> 1;

    const int m0 = blockIdx.x * 128;
    const int e0 = blockIdx.y * 128;

    const int sr = tid >> 2, sc = (tid & 3) * 8;
    const int n  = m0 >> 11;
    const int s0 = m0 & (SEQ - 1);
    const _Float16* Bw = Wps + (size_t)e0 * DMODEL;

    const f32x4 fzero = {0.f, 0.f, 0.f, 0.f};
    f32x4 acc[4][4];
    #pragma unroll
    for (int i = 0; i < 4; ++i)
        #pragma unroll
        for (int j = 0; j < 4; ++j) acc[i][j] = fzero;

    for (int kt = 0; kt < DMODEL; kt += 32) {
        const int h = (kt + sc) >> 6, dk = (kt + sc) & 63;   // 8-run in one head
        f16x8 pa[2], pb[2];
        #pragma unroll
        for (int f = 0; f < 2; ++f) {
            const int s = s0 + sr + 64 * f;
            pa[f] = *(const f16x8*)
                &Yg[((size_t)(n * NHEAD + h) * SEQ + s) * HDIM + dk];
            pb[f] = *(const f16x8*)(Bw + (size_t)(sr + 64 * f) * DMODEL + kt + sc);
        }
        __syncthreads();
        #pragma unroll
        for (int f = 0; f < 2; ++f) {
            *(f16x8*)&As[sr + 64 * f][sc] = pa[f];
            *(f16x8*)&Bs[sr + 64 * f][sc] = pb[f];
        }
        __syncthreads();

        f16x8 fa[4], fb[4];
        #pragma unroll
        for (int i = 0; i < 4; ++i)
            fa[i] = *(const f16x8*)&As[64 * wm + 16 * i + col][8 * g];
        #pragma unroll
        for (int j = 0; j < 4; ++j)
            fb[j] = *(const f16x8*)&Bs[64 * we + 16 * j + col][8 * g];
        #pragma unroll
        for (int i = 0; i < 4; ++i)
            #pragma unroll
            for (int j = 0; j < 4; ++j)
                acc[i][j] = MFMA16(fa[i], fb[j], acc[i][j]);
    }

    #pragma unroll
    for (int i = 0; i < 4; ++i)
        #pragma unroll
        for (int j = 0; j < 4; ++j) {
            const int e = e0 + 64 * we + 16 * j + col;
            const float bb = bp[e];
            #pragma unroll
            for (int r = 0; r < 4; ++r) {
                const int m = m0 + 64 * wm + 16 * i + 4 * g + r;
                out[(size_t)m * DMODEL + e] = acc[i][j][r] + bb;
            }
        }
}

// ---------------------------------------------------------------------------
extern "C" void kernel_launch(void* const* d_in, const int* in_sizes, int n_in,
                              void* d_out, int out_size, void* d_ws, size_t ws_size,
                              hipStream_t stream) {
    (void)in_sizes; (void)n_in; (void)out_size; (void)ws_size;
    const float* x  = (const float*)d_in[0];
    const float* Wq = (const float*)d_in[1];
    const float* bq = (const float*)d_in[2];
    const float* Wk = (const float*)d_in[3];
    const float* bk = (const float*)d_in[4];
    const float* Wv = (const float*)d_in[5];
    const float* bv = (const float*)d_in[6];
    const float* Wp = (const float*)d_in[7];
    const float* bp = (const float*)d_in[8];
    float* out = (float*)d_out;

    // workspace carve (72 MiB):
    //   Wqs/Wks/Wvs/Wps f16: 2 MiB each           [0, 8)
    //   Qg  f16 [64][2048][64] (pre-scaled)       [8, 24)
    //   Kg  f16 [64][2048][64]                    [24, 40)
    //   Vtg f16 [64][64][2048]                    [40, 56)
    //   Yg  f16 [64][2048][64]                    [56, 72)
    const size_t MiB = 1048576;
    char* wsb = (char*)d_ws;
    _Float16* Wqs = (_Float16*)(wsb);
    _Float16* Wks = (_Float16*)(wsb + 2 * MiB);
    _Float16* Wvs = (_Float16*)(wsb + 4 * MiB);
    _Float16* Wps = (_Float16*)(wsb + 6 * MiB);
    _Float16* Qg  = (_Float16*)(wsb + 8 * MiB);
    _Float16* Kg  = (_Float16*)(wsb + 24 * MiB);
    _Float16* Vtg = (_Float16*)(wsb + 40 * MiB);
    _Float16* Yg  = (_Float16*)(wsb + 56 * MiB);

    cvtw_k<<<dim3(512, 4), 256, 0, stream>>>(
        Wq, Wk, Wv, Wp, Wqs, Wks, Wvs, Wps);

    qkv3_k<<<dim3(8192 / 128, 24), 256, 0, stream>>>(
        x, Wqs, Wks, Wvs, bq, bk, bv, Qg, Kg, Vtg);

    attn3_k<<<dim3(SEQ / 128, NH_TOT), 256, 0, stream>>>(
        Qg, Kg, Vtg, Yg);

    proj3_k<<<dim3(8192 / 128, DMODEL / 128), 256, 0, stream>>>(
        Yg, Wps, bp, out);
}